// Round 3
// baseline (114.839 us; speedup 1.0000x reference)
//
#include <hip/hip_runtime.h>

// STFT: x[16, 262144] fp32, Hann 2048, hop 512, reflect pad 1024.
// Output: real[16,1025,513] ++ imag[16,1025,513], fp32.
//
// Round 10: de-lockstep. R9 showed full residency (32 waves/CU) but all pipes
// idle (VALU 35%, HBM 28%, LDS ~19%) and dur ~= SUM of per-pipe times: the 6
// block-wide barriers kept all waves in the same phase, so load/LDS/VALU
// phases alternated CU-wide instead of overlapping. This round exploits that
// trips 1-3 are wave-local in data (wave w = plane w>>2, chunk w&3 only
// touches its own 512-point chunk) and remaps the loader so each wave loads
// exactly its own chunk (chunk cc <=> n mod 4 == rev2(cc);
// brev11(n) = cc*512 + brev9(n>>2)):
//  - Barriers 6 -> 2 (pre-quad, pre-epilogue). Load + 3 octet trips are
//    barrier-free per wave, fenced only by that wave's own s_waitcnt
//    lgkmcnt(0) (+ sched_barrier, rule: inline waitcnt needs a sched fence).
//  - 32 waves/CU now run at independent phases -> VALU/LDS/HBM overlap.
//  - Loader global reads become 16B-stride/lane, but the 4 sibling waves of
//    a plane read complementary n mod 4 of the SAME frames -> L1 reuse,
//    FETCH ~flat.
//  - Everything else identical to R9: 512 threads, 2 planes, 33.8 KB LDS,
//    4 blocks/CU, octet swizzle for XCD-local write merging, radix-8 x3 +
//    radix-4 core, sincos twiddles, conjugate-symmetry epilogue.

#define N_FFT   2048
#define LOG2N   11
#define HOP     512
#define PADL    1024
#define NBINS   1025
#define NFRAMES 513
#define NBATCH  16
#define TLEN    262144

#define HALF_OUT ((size_t)NBATCH * NBINS * NFRAMES)   // 8,413,200 floats per plane

// wave-local fence: all my LDS ops done & visible; compiler may not reorder
#define WFENCE() do { \
    asm volatile("s_waitcnt lgkmcnt(0)" ::: "memory"); \
    __builtin_amdgcn_sched_barrier(0); \
} while (0)

__device__ __forceinline__ int pidx(int a) { return a + (a >> 5); }

__device__ __forceinline__ int refl(int j) {
    if (j < 0)          j = -j;
    else if (j >= TLEN) j = 2 * TLEN - 2 - j;
    return j;
}

__device__ __forceinline__ float2 cmul(float2 a, float2 w) {
    return make_float2(fmaf(a.x, w.x, -a.y * w.y), fmaf(a.x, w.y, a.y * w.x));
}
__device__ __forceinline__ float2 cadd(float2 a, float2 b) {
    return make_float2(a.x + b.x, a.y + b.y);
}
__device__ __forceinline__ float2 csub(float2 a, float2 b) {
    return make_float2(a.x - b.x, a.y - b.y);
}
__device__ __forceinline__ float2 csqr(float2 w) {
    return make_float2(fmaf(w.x, w.x, -w.y * w.y), 2.0f * w.x * w.y);
}

// Three DIT stages (halves H, 2H, 4H) on points base + m*H, m=0..7, in registers.
template <int H, int L2H>
__device__ __forceinline__ void octet_pass(float2* __restrict__ zc, int q) {
    const int p    = q & (H - 1);
    const int base = ((q >> L2H) << (L2H + 3)) + p;
    int ia[8];
#pragma unroll
    for (int m = 0; m < 8; ++m) ia[m] = pidx(base + m * H);
    float2 v0 = zc[ia[0]], v1 = zc[ia[1]], v2 = zc[ia[2]], v3 = zc[ia[3]];
    float2 v4 = zc[ia[4]], v5 = zc[ia[5]], v6 = zc[ia[6]], v7 = zc[ia[7]];

    float2 w1, w2, w3;
    if (H == 1) {
        w3 = make_float2(1.0f, 0.0f); w2 = w3; w1 = w3;   // p==0 always
    } else {
        float s, c;
        __sincosf((float)p * (-3.14159265358979323846f / (4.0f * (float)H)), &s, &c);
        w3 = make_float2(c, s);
        w2 = csqr(w3);
        w1 = csqr(w2);
    }

    float2 t;
    // stage A (half=H): pairs (0,1)(2,3)(4,5)(6,7), all twiddle w1
    t = cmul(v1, w1); v1 = csub(v0, t); v0 = cadd(v0, t);
    t = cmul(v3, w1); v3 = csub(v2, t); v2 = cadd(v2, t);
    t = cmul(v5, w1); v5 = csub(v4, t); v4 = cadd(v4, t);
    t = cmul(v7, w1); v7 = csub(v6, t); v6 = cadd(v6, t);
    // stage B (half=2H): pairs (0,2)(4,6) w2 ; (1,3)(5,7) -i*w2
    const float2 w2m = make_float2(w2.y, -w2.x);
    t = cmul(v2, w2);  v2 = csub(v0, t); v0 = cadd(v0, t);
    t = cmul(v3, w2m); v3 = csub(v1, t); v1 = cadd(v1, t);
    t = cmul(v6, w2);  v6 = csub(v4, t); v4 = cadd(v4, t);
    t = cmul(v7, w2m); v7 = csub(v5, t); v5 = cadd(v5, t);
    // stage C (half=4H): pairs (0,4) w3 ; (1,5) w3*e^{-i pi/4} ; (2,6) -i*w3 ; (3,7) -i*w3*e^{-i pi/4}
    const float R = 0.70710678118654752f;
    const float2 w3o  = make_float2((w3.x + w3.y) * R, (w3.y - w3.x) * R);
    const float2 w3m  = make_float2(w3.y, -w3.x);
    const float2 w3mo = make_float2(w3o.y, -w3o.x);
    t = cmul(v4, w3);   v4 = csub(v0, t); v0 = cadd(v0, t);
    t = cmul(v5, w3o);  v5 = csub(v1, t); v1 = cadd(v1, t);
    t = cmul(v6, w3m);  v6 = csub(v2, t); v2 = cadd(v2, t);
    t = cmul(v7, w3mo); v7 = csub(v3, t); v3 = cadd(v3, t);

    zc[ia[0]] = v0; zc[ia[1]] = v1; zc[ia[2]] = v2; zc[ia[3]] = v3;
    zc[ia[4]] = v4; zc[ia[5]] = v5; zc[ia[6]] = v6; zc[ia[7]] = v7;
}

__global__ __launch_bounds__(512, 8) void stft_one(
    const float* __restrict__ x,
    const float* __restrict__ window,
    float* __restrict__ out)
{
    __shared__ float2 z[2][2113];     // 2 packed FFTs, 33,808 B -> 4 blocks/CU

    // Block id mapping: d in [0,2048) covers (b, g) for g in [0,128); octets
    // of consecutive g (one 128 B output-line span) get ids differing by 8
    // (same XCD under round-robin) in adjacent slots (co-resident in time).
    // d in [2048,2064): tail blocks, one per batch, frame 512 only.
    const int d = blockIdx.x;
    int b, g;
    if (d >= 2048) {
        b = d - 2048;
        g = 128;
    } else {
        const int xcd  = d & 7;
        const int slot = d >> 3;                  // [0,256)
        const int O    = (slot >> 3) * 8 + xcd;   // octet id [0,256)
        const int L    = O * 8 + (slot & 7);      // logical block [0,2048)
        b = L >> 7;
        g = L & 127;
    }
    const int tid = threadIdx.x;
    const int f0  = g * 4;
    const int npl = (g == 128) ? 1 : 2;           // planes (packed FFTs)

    // wave-local identity: wave w owns plane c = w>>2, 512-pt chunk cc = w&3
    const int l  = tid & 63;
    const int c  = tid >> 8;                      // = (tid>>6)>>2
    const int cc = (tid >> 6) & 3;
    const int q  = tid & 255;                     // = cc*64 + l

    // ---- wave-local load: chunk cc <=> n mod 4 == rev2(cc) ----
    // brev11(n) = cc*512 + brev9(n>>2), so each wave fills exactly its chunk.
    if (c < npl) {
        const float* xb = x + (size_t)b * TLEN;
        const int nb = ((cc & 1) << 1) | (cc >> 1);   // rev2(cc)
        const int fa = f0 + 2 * c;
        const int a0 = fa * HOP - PADL;
#pragma unroll
        for (int jj = 0; jj < 8; ++jj) {
            const int j = (jj << 6) | l;              // 0..511
            const int n = (j << 2) | nb;
            const float w  = window[n];
            const float va = xb[refl(a0 + n)] * w;
            const float vb = xb[refl(a0 + HOP + n)] * w;   // next frame; phantom ok
            const int r = (cc << 9) | (int)(__brev((unsigned)j) >> 23);  // brev9(j)
            z[c][pidx(r)] = make_float2(va, vb);
        }

        // ---- stages 1-9: three radix-8 trips, wave-local, no __syncthreads ----
        WFENCE();
        octet_pass<1, 0>(z[c], q);
        WFENCE();
        octet_pass<8, 3>(z[c], q);
        WFENCE();
        octet_pass<64, 6>(z[c], q);
    }
    __syncthreads();

    // ---- stages 10-11: radix-4 quad pass (h=512), cross-chunk ----
    for (int idx = tid; idx < npl * 512; idx += 512) {
        const int cq = idx >> 9;
        const int p  = idx & 511;
        float s, ccs;
        __sincosf((float)p * (-3.14159265358979323846f / 1024.0f), &s, &ccs);
        const float2 w2  = make_float2(ccs, s);       // exp(-i*pi*p/1024)
        const float2 w1  = csqr(w2);                  // exp(-i*pi*p/512)
        const float2 w2m = make_float2(w2.y, -w2.x);  // -i*w2
        const int i0 = pidx(p), i1 = pidx(p + 512), i2 = pidx(p + 1024), i3 = pidx(p + 1536);
        float2 v0 = z[cq][i0], v1 = z[cq][i1], v2 = z[cq][i2], v3 = z[cq][i3];
        float2 t;
        // half=512: pairs (0,1)(2,3), twiddle w1
        t = cmul(v1, w1); v1 = csub(v0, t); v0 = cadd(v0, t);
        t = cmul(v3, w1); v3 = csub(v2, t); v2 = cadd(v2, t);
        // half=1024: pair (0,2) w2 ; pair (1,3) -i*w2
        t = cmul(v2, w2);  v2 = csub(v0, t); v0 = cadd(v0, t);
        t = cmul(v3, w2m); v3 = csub(v1, t); v1 = cadd(v1, t);
        z[cq][i0] = v0; z[cq][i1] = v1; z[cq][i2] = v2; z[cq][i3] = v3;
    }
    __syncthreads();

    // ---- unpack + direct write ----
    float* __restrict__ outr = out;
    float* __restrict__ outi = out + HALF_OUT;
    if (g < 128) {
        // planes 0,1 -> frames f0..f0+3; 16 B chunk per row; a wave covers
        // 64 consecutive k rows. Octet-swizzle makes the other 7 chunks of
        // each 128 B line co-resident on the same XCD.
        for (int k = tid; k < NBINS; k += 512) {
            const int km = (N_FFT - k) & (N_FFT - 1);
            const float2 zk0 = z[0][pidx(k)];
            const float2 zr0 = z[0][pidx(km)];
            const float2 zk1 = z[1][pidx(k)];
            const float2 zr1 = z[1][pidx(km)];
            const size_t o = ((size_t)b * NBINS + (size_t)k) * NFRAMES + (size_t)f0;
            outr[o + 0] = 0.5f * (zk0.x + zr0.x);   // even frame re
            outr[o + 1] = 0.5f * (zk0.y + zr0.y);   // odd frame re
            outr[o + 2] = 0.5f * (zk1.x + zr1.x);
            outr[o + 3] = 0.5f * (zk1.y + zr1.y);
            outi[o + 0] = 0.5f * (zk0.y - zr0.y);   // even frame im
            outi[o + 1] = 0.5f * (zr0.x - zk0.x);   // odd frame im
            outi[o + 2] = 0.5f * (zk1.y - zr1.y);
            outi[o + 3] = 0.5f * (zr1.x - zk1.x);
        }
    } else {
        // tail: frame 512 is the real part of the single packed FFT
        for (int k = tid; k < NBINS; k += 512) {
            const int km = (N_FFT - k) & (N_FFT - 1);
            const float2 zk = z[0][pidx(k)];
            const float2 zr = z[0][pidx(km)];
            const size_t o = ((size_t)b * NBINS + (size_t)k) * NFRAMES + 512;
            outr[o] = 0.5f * (zk.x + zr.x);
            outi[o] = 0.5f * (zk.y - zr.y);
        }
    }
}

extern "C" void kernel_launch(void* const* d_in, const int* in_sizes, int n_in,
                              void* d_out, int out_size, void* d_ws, size_t ws_size,
                              hipStream_t stream) {
    const float* x      = (const float*)d_in[0];
    const float* window = (const float*)d_in[1];
    float* out          = (float*)d_out;

    dim3 grid(2064);   // 2048 main + 16 tail blocks; d_ws deliberately unused
    stft_one<<<grid, 512, 0, stream>>>(x, window, out);
}